// Round 3
// baseline (337.931 us; speedup 1.0000x reference)
//
#include <hip/hip_runtime.h>
#include <hip/hip_bf16.h>
#include <stdint.h>

typedef unsigned short u16;
typedef short bf16x8 __attribute__((ext_vector_type(8)));
typedef float f32x4 __attribute__((ext_vector_type(4)));
typedef u16 u16x8 __attribute__((ext_vector_type(8)));

#define DEVFN static __device__ __forceinline__

// sizes
#define NB 16
#define CIN 256
#define HH 64
#define WW 64
#define COUT 512
#define NEXP 8
#define NPX 4096           // 64*64
#define NSTEP 72           // 8 ci-blocks * 9 shifts

DEVFN u16 bf16_rne(float f){
  union { float f; uint32_t u; } v; v.f = f;
  uint32_t u = v.u;
  return (u16)((u + 0x7fffu + ((u >> 16) & 1u)) >> 16);
}

DEVFN void gload16(const void* g, void* l){
  __builtin_amdgcn_global_load_lds((const __attribute__((address_space(1))) void*)g,
                                   (__attribute__((address_space(3))) void*)l,
                                   16, 0, 0);
}

#define VMWAIT(N) asm volatile("s_waitcnt vmcnt(" #N ")" ::: "memory")
#define BARRIER() do { __builtin_amdgcn_s_barrier(); \
                       __builtin_amdgcn_sched_barrier(0); \
                       asm volatile("" ::: "memory"); } while(0)

// ---------------- pooled = mean over HW ----------------
__global__ void k_pool(const float* __restrict__ x, float* __restrict__ pooled){
  int bc = blockIdx.x;                       // 0..4095 = b*256+c
  const float4* p4 = (const float4*)(x + (size_t)bc * NPX);
  int t = threadIdx.x;
  float s = 0.f;
  for (int i = t; i < NPX/4; i += 256){ float4 v = p4[i]; s += v.x+v.y+v.z+v.w; }
  for (int o = 32; o; o >>= 1) s += __shfl_down(s, o);
  __shared__ float ls[4];
  if ((t & 63) == 0) ls[t >> 6] = s;
  __syncthreads();
  if (t == 0) pooled[bc] = (ls[0]+ls[1]+ls[2]+ls[3]) * (1.0f/ (float)NPX);
}

// ---------------- routing = sigmoid(pooled @ fcw^T + fcb) ----------------
__global__ void k_route(const float* __restrict__ pooled, const float* __restrict__ fcw,
                        const float* __restrict__ fcb, float* __restrict__ routing){
  int bk = blockIdx.x;              // 0..127
  int b = bk >> 3, k = bk & 7;
  int l = threadIdx.x;              // 64
  float4 pv = ((const float4*)(pooled + b*CIN))[l];
  float4 wv = ((const float4*)(fcw   + k*CIN))[l];
  float s = pv.x*wv.x + pv.y*wv.y + pv.z*wv.z + pv.w*wv.w;
  for (int o = 32; o; o >>= 1) s += __shfl_down(s, o);
  if (l == 0) routing[b*8 + k] = 1.0f / (1.0f + __expf(-(s + fcb[k])));
}

// ---------------- combined bias ----------------
__global__ void k_cbias(const float* __restrict__ routing, const float* __restrict__ eb,
                        float* __restrict__ cbias){
  int idx = blockIdx.x*256 + threadIdx.x;   // 8192 = b*512+co
  int b = idx >> 9, co = idx & 511;
  float s = 0.f;
  for (int k = 0; k < 8; k++) s += routing[b*8+k] * eb[k*COUT + co];
  cbias[idx] = s;
}

// ---------------- combined weights -> bf16, layout [b][step][co][ci32] ----------------
__global__ void k_wcomb(const float* __restrict__ routing, const float* __restrict__ ew,
                        u16* __restrict__ wc){
  int blk  = blockIdx.x;            // 72*64 = 4608
  int step = blk >> 6;              // 0..71
  int cog  = blk & 63;
  int cb = step / 9, rs = step - cb*9;
  int t = threadIdx.x;
  int ci = t & 31, co = cog*8 + (t >> 5);
  int cig = cb*32 + ci;
  float wv[8];
#pragma unroll
  for (int k = 0; k < 8; k++)
    wv[k] = ew[(size_t)((k*COUT + co)*CIN + cig)*9 + rs];
  for (int b = 0; b < NB; b++){
    float s = 0.f;
#pragma unroll
    for (int k = 0; k < 8; k++) s += routing[b*8+k] * wv[k];
    wc[((size_t)(b*NSTEP + step)*COUT + co)*32 + ci] = bf16_rne(s);
  }
}

// ---------------- x -> padded transposed bf16: x_t[b][66][68][256] ----------------
__global__ void k_xprep(const float* __restrict__ x, u16* __restrict__ xt){
  int blk = blockIdx.x;             // 16*64*4 = 4096
  int ctile = blk & 3;
  int h = (blk >> 2) & 63;
  int b = blk >> 8;
  __shared__ u16 S[64][66];
  int t = threadIdx.x;
  {
    int ci_l = t >> 2, w0 = (t & 3) * 16;
    const float4* src = (const float4*)(x + ((size_t)((b*CIN + ctile*64 + ci_l)*HH + h)*WW + w0));
    float4 a = src[0], bb = src[1], c = src[2], d = src[3];
    u16* row = &S[ci_l][w0];
    row[0]=bf16_rne(a.x);  row[1]=bf16_rne(a.y);  row[2]=bf16_rne(a.z);  row[3]=bf16_rne(a.w);
    row[4]=bf16_rne(bb.x); row[5]=bf16_rne(bb.y); row[6]=bf16_rne(bb.z); row[7]=bf16_rne(bb.w);
    row[8]=bf16_rne(c.x);  row[9]=bf16_rne(c.y);  row[10]=bf16_rne(c.z); row[11]=bf16_rne(c.w);
    row[12]=bf16_rne(d.x); row[13]=bf16_rne(d.y); row[14]=bf16_rne(d.z); row[15]=bf16_rne(d.w);
  }
  __syncthreads();
  {
    int w_l = t >> 2, cig = (t & 3) * 16;
    u16x8 v0, v1;
#pragma unroll
    for (int j = 0; j < 8; j++){ v0[j] = S[cig+j][w_l]; v1[j] = S[cig+8+j][w_l]; }
    u16* dst = xt + ((size_t)(b*66 + h + 1)*68 + (w_l + 1))*CIN + ctile*64 + cig;
    *(u16x8*)(dst)     = v0;
    *(u16x8*)(dst + 8) = v1;
  }
}

// ---------------- the conv: implicit GEMM, 128co x 128px tiles ----------------
#define XBYTES 17408      // 4*68*32*2
#define WBYTES 8192       // 128*32*2

// stage one 128co x 32ci W tile (512 16B chunks, 2 per lane), pre-swizzled source.
// Trailing sched_barrier(0) seals this load group: vmcnt accounting relies on
// load groups retiring in PROGRAM order (vmcnt is a FIFO).
DEVFN void stage_w(const u16* __restrict__ wstep, char* dst, int wv, int l){
#pragma unroll
  for (int i = 0; i < 2; i++){
    int q = i*256 + wv*64 + l;
    int co_l = q >> 2, j = q & 3;
    gload16(wstep + co_l*32 + ((j ^ ((co_l >> 1) & 3)) << 3), dst + (i*256 + wv*64)*16);
  }
  __builtin_amdgcn_sched_barrier(0);
}

// stage one 4row x 68col x 32ci X tile (1088 chunks, dup-padded to uniform 5/lane)
DEVFN void stage_x(const u16* __restrict__ xtb, int h0, int cioff, char* dst, int wv, int l){
#pragma unroll
  for (int i = 0; i < 5; i++){
    int qb = i*256 + wv*64;
    if (qb >= 1088) qb -= 1088;          // dup-write low chunks (same data, benign)
    int q = qb + l;
    int t2 = q >> 2;
    int lr = (t2 * 964) >> 16;           // /68 for t2<272
    int c  = t2 - lr*68;
    int j  = q & 3;
    gload16(xtb + ((size_t)(h0 + lr)*68 + c)*CIN + cioff + ((j ^ ((c >> 1) & 3)) << 3),
            dst + qb*16);
  }
  __builtin_amdgcn_sched_barrier(0);
}

template<int RS>
DEVFN void conv_step(int cb, char* w0, char* w1, char* w2,
                     const char* Xc, char* Xn,
                     const u16* __restrict__ xtb, const u16* __restrict__ wcb, int h0,
                     int wv, int l, int wn, int l15, int kbq, int byteA0,
                     f32x4 acc[4][4])
{
  constexpr int r = RS / 3, s = RS - r*3;
  char* Wc = (RS % 3 == 0) ? w0 : (RS % 3 == 1) ? w1 : w2;
  char* Wp = ((RS+2) % 3 == 0) ? w0 : ((RS+2) % 3 == 1) ? w1 : w2;

  // C: fragment ds_reads (data guaranteed by previous step's wait+barrier)
  int c0 = l15 + s;
  int byteB0 = ((wn + r)*68 + c0)*64 + ((kbq ^ ((c0 >> 1) & 3)) << 4);
  bf16x8 af[4], bfr[4];
#pragma unroll
  for (int m = 0; m < 4; m++) af[m]  = *(const bf16x8*)(Wc + byteA0 + m*1024);
#pragma unroll
  for (int n = 0; n < 4; n++) bfr[n] = *(const bf16x8*)(Xc + byteB0 + n*1024);

  // A: prefetch issue (stays in flight across the barrier — counted vmcnt).
  // Order within a step is pinned (sched_barrier in stage_*): W pair first, X batch second.
  if constexpr (RS < 7) {
    stage_w(wcb + (size_t)(cb*9 + RS + 2)*(COUT*32), Wp, wv, l);
  } else {
    if (cb != 7) stage_w(wcb + (size_t)(cb*9 + RS + 2)*(COUT*32), Wp, wv, l);
  }
  if constexpr (RS == 5) {
    if (cb != 7) stage_x(xtb, h0, (cb+1)*32, Xn, wv, l);
  }

  // D: MFMA
  __builtin_amdgcn_s_setprio(1);
#pragma unroll
  for (int m = 0; m < 4; m++)
#pragma unroll
    for (int n = 0; n < 4; n++)
      acc[m][n] = __builtin_amdgcn_mfma_f32_16x16x32_bf16(af[m], bfr[n], acc[m][n], 0, 0, 0);
  __builtin_amdgcn_s_setprio(0);

  // E: counted wait + raw barrier.  FIFO per wave (W groups of 2, X group of 5):
  //  cb<7 : RS<=4 [Wn+1,Wn+2]->wait(2) ; RS=5 [Wn+1,Wn+2,X]->wait(7)
  //         RS=6 [Wn+1,X,Wn+2]->wait(7) ; RS=7 [X,Wn+1,Wn+2]->wait(2) ; RS=8 wait(2)
  //  cb==7: no X batch; RS5/6 wait(2); RS7 drain(0); RS8 fallthrough to epilogue.
  if constexpr (RS <= 4)      { VMWAIT(2); BARRIER(); }
  else if constexpr (RS == 5 || RS == 6) {
    if (cb != 7) { VMWAIT(7); } else { VMWAIT(2); }
    BARRIER();
  }
  else if constexpr (RS == 7) {
    if (cb != 7) { VMWAIT(2); } else { VMWAIT(0); }
    BARRIER();
  }
  else                        { if (cb != 7) { VMWAIT(2); BARRIER(); } }
}

__global__ __launch_bounds__(256, 2) void k_conv(
    const u16* __restrict__ xt, const u16* __restrict__ wc,
    const float* __restrict__ cbias, float* __restrict__ out,
    float* __restrict__ ssum, float* __restrict__ ssq)
{
  __shared__ char lds[3*WBYTES + 2*XBYTES];    // 59392
  char* w0  = lds;
  char* w1  = lds + WBYTES;
  char* w2  = lds + 2*WBYTES;
  char* Xb0 = lds + 3*WBYTES;
  char* Xb1 = lds + 3*WBYTES + XBYTES;

  int hw = blockIdx.x;                       // 2048 blocks
  int lb = (hw & 7) * 256 + (hw >> 3);       // XCD-aware swizzle (2048%8==0, bijective)
  int b  = lb >> 7;
  int ct = (lb >> 5) & 3;
  int pt = lb & 31;
  int h0 = pt * 2;

  int t = threadIdx.x, l = t & 63, wv = t >> 6;
  int wm = wv >> 1, wn = wv & 1;
  int l15 = l & 15, kbq = l >> 4;

  const u16* xtb = xt + (size_t)b * 66*68*CIN;
  const u16* wcb = wc + (size_t)(b*NSTEP) * COUT*32 + ct*128*32;

  f32x4 acc[4][4];
#pragma unroll
  for (int m = 0; m < 4; m++)
#pragma unroll
    for (int n = 0; n < 4; n++) acc[m][n] = (f32x4){0.f,0.f,0.f,0.f};

  const int byteA0 = (wm*64 + l15)*64 + ((kbq ^ ((l15 >> 1) & 3)) << 4);

  // prologue: X(cb=0), W(0), W(1); wait X0+W0 landed (W1 stays in flight)
  stage_x(xtb, h0, 0, Xb0, wv, l);
  stage_w(wcb, w0, wv, l);
  stage_w(wcb + COUT*32, w1, wv, l);
  VMWAIT(2);
  BARRIER();

  for (int cb = 0; cb < 8; cb++){
    char* Xc = (cb & 1) ? Xb1 : Xb0;
    char* Xn = (cb & 1) ? Xb0 : Xb1;
    conv_step<0>(cb, w0,w1,w2, Xc,Xn, xtb,wcb,h0, wv,l,wn,l15,kbq,byteA0, acc);
    conv_step<1>(cb, w0,w1,w2, Xc,Xn, xtb,wcb,h0, wv,l,wn,l15,kbq,byteA0, acc);
    conv_step<2>(cb, w0,w1,w2, Xc,Xn, xtb,wcb,h0, wv,l,wn,l15,kbq,byteA0, acc);
    conv_step<3>(cb, w0,w1,w2, Xc,Xn, xtb,wcb,h0, wv,l,wn,l15,kbq,byteA0, acc);
    conv_step<4>(cb, w0,w1,w2, Xc,Xn, xtb,wcb,h0, wv,l,wn,l15,kbq,byteA0, acc);
    conv_step<5>(cb, w0,w1,w2, Xc,Xn, xtb,wcb,h0, wv,l,wn,l15,kbq,byteA0, acc);
    conv_step<6>(cb, w0,w1,w2, Xc,Xn, xtb,wcb,h0, wv,l,wn,l15,kbq,byteA0, acc);
    conv_step<7>(cb, w0,w1,w2, Xc,Xn, xtb,wcb,h0, wv,l,wn,l15,kbq,byteA0, acc);
    conv_step<8>(cb, w0,w1,w2, Xc,Xn, xtb,wcb,h0, wv,l,wn,l15,kbq,byteA0, acc);
  }

  // ---- epilogue: bias add, store raw, fused BN partial sums ----
  int co_t = ct*128 + wm*64 + (kbq << 2);
  int px_t = pt*128 + wn*64 + l15;
  float* outb = out + (size_t)b * COUT * NPX;
#pragma unroll
  for (int m = 0; m < 4; m++){
#pragma unroll
    for (int rg = 0; rg < 4; rg++){
      int co = co_t + m*16 + rg;
      float bias = cbias[b*COUT + co];
      float s1 = 0.f, s2 = 0.f;
      size_t base = (size_t)co * NPX + px_t;
#pragma unroll
      for (int n = 0; n < 4; n++){
        float v = acc[m][n][rg] + bias;
        outb[base + n*16] = v;
        s1 += v; s2 += v*v;
      }
#pragma unroll
      for (int o = 8; o; o >>= 1){ s1 += __shfl_xor(s1, o); s2 += __shfl_xor(s2, o); }
      if (l15 == 0){ atomicAdd(&ssum[co], s1); atomicAdd(&ssq[co], s2); }
    }
  }
}

// ---------------- finalize BN scale/shift ----------------
__global__ void k_stats(const float* __restrict__ ssum, const float* __restrict__ ssq,
                        const float* __restrict__ gamma, const float* __restrict__ beta,
                        float* __restrict__ sc, float* __restrict__ sh){
  int co = blockIdx.x*256 + threadIdx.x;    // 512
  const float invN = 1.0f / 65536.0f;
  float m  = ssum[co] * invN;
  float var = ssq[co] * invN - m*m;
  float scale = gamma[co] * rsqrtf(var + 1e-5f);
  sc[co] = scale;
  sh[co] = beta[co] - m*scale;
}

// ---------------- normalize + LeakyReLU (in place on d_out) ----------------
__global__ void k_norm(float* __restrict__ out, const float* __restrict__ sc,
                       const float* __restrict__ sh){
  const int NF4 = (NB*COUT*NPX)/4;          // 8388608
  int idx = blockIdx.x*256 + threadIdx.x;   // grid 8192*256
  float4* o4 = (float4*)out;
  for (int i = idx; i < NF4; i += 8192*256){
    float4 v = o4[i];
    int co = (i >> 10) & 511;
    float a = sc[co], d = sh[co];
    v.x = fmaf(v.x, a, d); v.y = fmaf(v.y, a, d);
    v.z = fmaf(v.z, a, d); v.w = fmaf(v.w, a, d);
    v.x = v.x > 0.f ? v.x : 0.1f*v.x;
    v.y = v.y > 0.f ? v.y : 0.1f*v.y;
    v.z = v.z > 0.f ? v.z : 0.1f*v.z;
    v.w = v.w > 0.f ? v.w : 0.1f*v.w;
    o4[i] = v;
  }
}

extern "C" void kernel_launch(void* const* d_in, const int* in_sizes, int n_in,
                              void* d_out, int out_size, void* d_ws, size_t ws_size,
                              hipStream_t stream) {
  const float* x     = (const float*)d_in[0];
  const float* ew    = (const float*)d_in[1];
  const float* eb    = (const float*)d_in[2];
  const float* fcw   = (const float*)d_in[3];
  const float* fcb   = (const float*)d_in[4];
  const float* gamma = (const float*)d_in[5];
  const float* beta  = (const float*)d_in[6];
  float* out = (float*)d_out;

  char* ws = (char*)d_ws;
  const size_t XT_BYTES = (size_t)NB*66*68*CIN*2;          // 36,765,696
  const size_t WC_BYTES = (size_t)NB*NSTEP*COUT*32*2;      // 37,748,736
  u16* xt = (u16*)ws;
  u16* wc = (u16*)(ws + XT_BYTES);
  float* fbase   = (float*)(ws + XT_BYTES + WC_BYTES);
  float* pooled  = fbase;                 // 4096
  float* routing = fbase + 4096;          // 128
  float* cbias   = fbase + 4096 + 128;    // 8192
  float* ssum    = cbias + 8192;          // 512
  float* ssq     = ssum + 512;            // 512
  float* sc      = ssq + 512;             // 512
  float* sh      = sc + 512;              // 512

  hipMemsetAsync(xt, 0, XT_BYTES, stream);
  hipMemsetAsync(ssum, 0, 2*512*sizeof(float), stream);

  k_pool <<<4096, 256, 0, stream>>>(x, pooled);
  k_xprep<<<4096, 256, 0, stream>>>(x, xt);
  k_route<<<128,   64, 0, stream>>>(pooled, fcw, fcb, routing);
  k_cbias<<<32,   256, 0, stream>>>(routing, eb, cbias);
  k_wcomb<<<4608, 256, 0, stream>>>(routing, ew, wc);
  k_conv <<<2048, 256, 0, stream>>>(xt, wc, cbias, out, ssum, ssq);
  k_stats<<<2,    256, 0, stream>>>(ssum, ssq, gamma, beta, sc, sh);
  k_norm <<<8192, 256, 0, stream>>>(out, sc, sh);
}

// Round 4
// 313.211 us; speedup vs baseline: 1.0789x; 1.0789x over previous
//
#include <hip/hip_runtime.h>
#include <hip/hip_bf16.h>
#include <stdint.h>

typedef unsigned short u16;
typedef short bf16x8 __attribute__((ext_vector_type(8)));
typedef float f32x4 __attribute__((ext_vector_type(4)));
typedef u16 u16x8 __attribute__((ext_vector_type(8)));

#define DEVFN static __device__ __forceinline__

// sizes
#define NB 16
#define CIN 256
#define HH 64
#define WW 64
#define COUT 512
#define NPX 4096           // 64*64
#define NSTEP 72           // 8 ci-blocks * 9 shifts

DEVFN u16 bf16_rne(float f){
  union { float f; uint32_t u; } v; v.f = f;
  uint32_t u = v.u;
  return (u16)((u + 0x7fffu + ((u >> 16) & 1u)) >> 16);
}

DEVFN void gload16(const void* g, void* l){
  __builtin_amdgcn_global_load_lds((const __attribute__((address_space(1))) void*)g,
                                   (__attribute__((address_space(3))) void*)l,
                                   16, 0, 0);
}

#define VMWAIT(N) asm volatile("s_waitcnt vmcnt(" #N ")" ::: "memory")
#define BARRIER() do { __builtin_amdgcn_s_barrier(); \
                       __builtin_amdgcn_sched_barrier(0); \
                       asm volatile("" ::: "memory"); } while(0)

// ---------------- routing = sigmoid((pooled_sum/4096) @ fcw^T + fcb) ----------------
__global__ void k_route(const float* __restrict__ pooled, const float* __restrict__ fcw,
                        const float* __restrict__ fcb, float* __restrict__ routing){
  int bk = blockIdx.x;              // 0..127
  int b = bk >> 3, k = bk & 7;
  int l = threadIdx.x;              // 64
  float4 pv = ((const float4*)(pooled + b*CIN))[l];
  float4 wv = ((const float4*)(fcw   + k*CIN))[l];
  float s = pv.x*wv.x + pv.y*wv.y + pv.z*wv.z + pv.w*wv.w;
  for (int o = 32; o; o >>= 1) s += __shfl_down(s, o);
  if (l == 0) routing[b*8 + k] = 1.0f / (1.0f + __expf(-(s * (1.0f/(float)NPX) + fcb[k])));
}

// ---------------- combined bias ----------------
__global__ void k_cbias(const float* __restrict__ routing, const float* __restrict__ eb,
                        float* __restrict__ cbias){
  int idx = blockIdx.x*256 + threadIdx.x;   // 8192 = b*512+co
  int b = idx >> 9, co = idx & 511;
  float s = 0.f;
  for (int k = 0; k < 8; k++) s += routing[b*8+k] * eb[k*COUT + co];
  cbias[idx] = s;
}

// ---------------- combined weights -> bf16, layout [b][step][co][ci32] ----------------
__global__ void k_wcomb(const float* __restrict__ routing, const float* __restrict__ ew,
                        u16* __restrict__ wc){
  int blk  = blockIdx.x;            // 72*64 = 4608
  int step = blk >> 6;              // 0..71
  int cog  = blk & 63;
  int cb = step / 9, rs = step - cb*9;
  int t = threadIdx.x;
  int ci = t & 31, co = cog*8 + (t >> 5);
  int cig = cb*32 + ci;
  float wv[8];
#pragma unroll
  for (int k = 0; k < 8; k++)
    wv[k] = ew[(size_t)((k*COUT + co)*CIN + cig)*9 + rs];
  for (int b = 0; b < NB; b++){
    float s = 0.f;
#pragma unroll
    for (int k = 0; k < 8; k++) s += routing[b*8+k] * wv[k];
    wc[((size_t)(b*NSTEP + step)*COUT + co)*32 + ci] = bf16_rne(s);
  }
}

// ---- x -> padded transposed bf16 x_t[b][66][68][256]  +  fused GAP partials ----
__global__ void k_xprep(const float* __restrict__ x, u16* __restrict__ xt,
                        float* __restrict__ pooled){
  int blk = blockIdx.x;             // 16*64*4 = 4096
  int ctile = blk & 3;
  int h = (blk >> 2) & 63;
  int b = blk >> 8;
  __shared__ u16 S[64][66];
  int t = threadIdx.x;
  {
    int ci_l = t >> 2, w0 = (t & 3) * 16;
    const float4* src = (const float4*)(x + ((size_t)((b*CIN + ctile*64 + ci_l)*HH + h)*WW + w0));
    float4 a = src[0], bb = src[1], c = src[2], d = src[3];
    u16* row = &S[ci_l][w0];
    row[0]=bf16_rne(a.x);  row[1]=bf16_rne(a.y);  row[2]=bf16_rne(a.z);  row[3]=bf16_rne(a.w);
    row[4]=bf16_rne(bb.x); row[5]=bf16_rne(bb.y); row[6]=bf16_rne(bb.z); row[7]=bf16_rne(bb.w);
    row[8]=bf16_rne(c.x);  row[9]=bf16_rne(c.y);  row[10]=bf16_rne(c.z); row[11]=bf16_rne(c.w);
    row[12]=bf16_rne(d.x); row[13]=bf16_rne(d.y); row[14]=bf16_rne(d.z); row[15]=bf16_rne(d.w);
    // fused GAP partial: sum of the 16 loaded values, 4-lane tree, one atomic per ci
    float s = a.x+a.y+a.z+a.w + bb.x+bb.y+bb.z+bb.w + c.x+c.y+c.z+c.w + d.x+d.y+d.z+d.w;
    s += __shfl_down(s, 2);
    s += __shfl_down(s, 1);
    if ((t & 3) == 0) atomicAdd(&pooled[b*CIN + ctile*64 + ci_l], s);
  }
  __syncthreads();
  {
    int w_l = t >> 2, cig = (t & 3) * 16;
    u16x8 v0, v1;
#pragma unroll
    for (int j = 0; j < 8; j++){ v0[j] = S[cig+j][w_l]; v1[j] = S[cig+8+j][w_l]; }
    u16* dst = xt + ((size_t)(b*66 + h + 1)*68 + (w_l + 1))*CIN + ctile*64 + cig;
    *(u16x8*)(dst)     = v0;
    *(u16x8*)(dst + 8) = v1;
  }
}

// ---------------- the conv: implicit GEMM, 128co x 128px tiles ----------------
#define XBYTES 17408      // 4*68*32*2
#define WBYTES 8192       // 128*32*2

// stage one 128co x 32ci W tile (512 16B chunks, 2 per lane), pre-swizzled source.
// Trailing sched_barrier(0) seals this load group (vmcnt FIFO accounting).
DEVFN void stage_w(const u16* __restrict__ wstep, char* dst, int wv, int l){
#pragma unroll
  for (int i = 0; i < 2; i++){
    int q = i*256 + wv*64 + l;
    int co_l = q >> 2, j = q & 3;
    gload16(wstep + co_l*32 + ((j ^ ((co_l >> 1) & 3)) << 3), dst + (i*256 + wv*64)*16);
  }
  __builtin_amdgcn_sched_barrier(0);
}

// stage one 4row x 68col x 32ci X tile (1088 chunks, dup-padded to uniform 5/lane)
DEVFN void stage_x(const u16* __restrict__ xtb, int h0, int cioff, char* dst, int wv, int l){
#pragma unroll
  for (int i = 0; i < 5; i++){
    int qb = i*256 + wv*64;
    if (qb >= 1088) qb -= 1088;          // dup-write low chunks (same data, benign)
    int q = qb + l;
    int t2 = q >> 2;
    int lr = (t2 * 964) >> 16;           // /68 for t2<272
    int c  = t2 - lr*68;
    int j  = q & 3;
    gload16(xtb + ((size_t)(h0 + lr)*68 + c)*CIN + cioff + ((j ^ ((c >> 1) & 3)) << 3),
            dst + qb*16);
  }
  __builtin_amdgcn_sched_barrier(0);
}

// Step shape (T3-style): {ds_read frags(t) ; issue gloads ; counted vmwait ; barrier ;
// MFMA cluster}.  Reads are in flight during vmwait+barrier; other waves' MFMA
// clusters cover this wave's read window.  W ring of 4, issue distance 3.
template<int RS>
DEVFN void conv_step(int cb, char* ldsbase, const char* Xc, char* Xn,
                     const u16* __restrict__ xtb, const u16* __restrict__ wcb, int h0,
                     int wv, int l, int wn, int l15, int kbq, int byteA0,
                     f32x4 acc[4][4])
{
  constexpr int r = RS / 3, s = RS - r*3;
  const char* Wc = ldsbase + (((unsigned)(cb + RS)) & 3)*WBYTES;       // t%4, 9≡1 mod 4
  char* Wp       = ldsbase + (((unsigned)(cb + RS + 3)) & 3)*WBYTES;

  // a: fragment ds_reads for THIS step (W(t) published at previous barrier)
  int c0 = l15 + s;
  int byteB0 = ((wn + r)*68 + c0)*64 + ((kbq ^ ((c0 >> 1) & 3)) << 4);
  bf16x8 af[4], bfr[4];
#pragma unroll
  for (int m = 0; m < 4; m++) af[m]  = *(const bf16x8*)(Wc + byteA0 + m*1024);
#pragma unroll
  for (int n = 0; n < 4; n++) bfr[n] = *(const bf16x8*)(Xc + byteB0 + n*1024);

  // b: gload issue — W(t+3) (if t+3 <= 71), X(cb+1) at rs==4
  if constexpr (RS <= 5) {
    stage_w(wcb + (size_t)(cb*9 + RS + 3)*(COUT*32), Wp, wv, l);
  } else {
    if (cb != 7) stage_w(wcb + (size_t)(cb*9 + RS + 3)*(COUT*32), Wp, wv, l);
  }
  if constexpr (RS == 4) {
    if (cb != 7) stage_x(xtb, h0, (cb+1)*32, Xn, wv, l);
  }

  // c+d: counted wait (guarantee W(t+1) landed; leave newer in flight) + barrier.
  // FIFO: W issues 2/step, X issues 5 at rs==4.
  if constexpr (RS <= 3)      { VMWAIT(4); BARRIER(); }
  else if constexpr (RS == 4 || RS == 5) {
    if (cb != 7) { VMWAIT(9); } else { VMWAIT(4); }
    BARRIER();
  }
  else if constexpr (RS == 6) {
    if (cb != 7) { VMWAIT(9); } else { VMWAIT(2); }
    BARRIER();
  }
  else if constexpr (RS == 7) {
    if (cb != 7) { VMWAIT(4); } else { VMWAIT(0); }
    BARRIER();
  }
  else {                      // RS == 8
    if (cb != 7) { VMWAIT(4); BARRIER(); }
  }

  // e: MFMA cluster
  __builtin_amdgcn_s_setprio(1);
#pragma unroll
  for (int m = 0; m < 4; m++)
#pragma unroll
    for (int n = 0; n < 4; n++)
      acc[m][n] = __builtin_amdgcn_mfma_f32_16x16x32_bf16(af[m], bfr[n], acc[m][n], 0, 0, 0);
  __builtin_amdgcn_s_setprio(0);
}

__global__ __launch_bounds__(256, 2) void k_conv(
    const u16* __restrict__ xt, const u16* __restrict__ wc,
    const float* __restrict__ cbias, float* __restrict__ out,
    float* __restrict__ ssum, float* __restrict__ ssq)
{
  __shared__ char lds[4*WBYTES + 2*XBYTES];    // 67584
  char* Xb0 = lds + 4*WBYTES;
  char* Xb1 = lds + 4*WBYTES + XBYTES;

  int hw = blockIdx.x;                       // 2048 blocks
  int lb = (hw & 7) * 256 + (hw >> 3);       // XCD-aware swizzle (2048%8==0, bijective)
  int b  = lb >> 7;
  int ct = (lb >> 5) & 3;
  int pt = lb & 31;
  int h0 = pt * 2;

  int t = threadIdx.x, l = t & 63, wv = t >> 6;
  int wm = wv >> 1, wn = wv & 1;
  int l15 = l & 15, kbq = l >> 4;

  const u16* xtb = xt + (size_t)b * 66*68*CIN;
  const u16* wcb = wc + (size_t)(b*NSTEP) * COUT*32 + ct*128*32;

  f32x4 acc[4][4];
#pragma unroll
  for (int m = 0; m < 4; m++)
#pragma unroll
    for (int n = 0; n < 4; n++) acc[m][n] = (f32x4){0.f,0.f,0.f,0.f};

  const int byteA0 = (wm*64 + l15)*64 + ((kbq ^ ((l15 >> 1) & 3)) << 4);

  // prologue: X(0) -> Xb0; W0,W1,W2 -> ring slots 0,1,2.  Wait X0+W0 (leave W1,W2).
  stage_x(xtb, h0, 0, Xb0, wv, l);
  stage_w(wcb,             lds + 0*WBYTES, wv, l);
  stage_w(wcb + COUT*32,   lds + 1*WBYTES, wv, l);
  stage_w(wcb + 2*COUT*32, lds + 2*WBYTES, wv, l);
  VMWAIT(4);
  BARRIER();

  for (int cb = 0; cb < 8; cb++){
    char* Xc = (cb & 1) ? Xb1 : Xb0;
    char* Xn = (cb & 1) ? Xb0 : Xb1;
    conv_step<0>(cb, lds, Xc,Xn, xtb,wcb,h0, wv,l,wn,l15,kbq,byteA0, acc);
    conv_step<1>(cb, lds, Xc,Xn, xtb,wcb,h0, wv,l,wn,l15,kbq,byteA0, acc);
    conv_step<2>(cb, lds, Xc,Xn, xtb,wcb,h0, wv,l,wn,l15,kbq,byteA0, acc);
    conv_step<3>(cb, lds, Xc,Xn, xtb,wcb,h0, wv,l,wn,l15,kbq,byteA0, acc);
    conv_step<4>(cb, lds, Xc,Xn, xtb,wcb,h0, wv,l,wn,l15,kbq,byteA0, acc);
    conv_step<5>(cb, lds, Xc,Xn, xtb,wcb,h0, wv,l,wn,l15,kbq,byteA0, acc);
    conv_step<6>(cb, lds, Xc,Xn, xtb,wcb,h0, wv,l,wn,l15,kbq,byteA0, acc);
    conv_step<7>(cb, lds, Xc,Xn, xtb,wcb,h0, wv,l,wn,l15,kbq,byteA0, acc);
    conv_step<8>(cb, lds, Xc,Xn, xtb,wcb,h0, wv,l,wn,l15,kbq,byteA0, acc);
  }

  // ---- epilogue: bias add, store raw, fused BN partial sums ----
  int co_t = ct*128 + wm*64 + (kbq << 2);
  int px_t = pt*128 + wn*64 + l15;
  float* outb = out + (size_t)b * COUT * NPX;
#pragma unroll
  for (int m = 0; m < 4; m++){
#pragma unroll
    for (int rg = 0; rg < 4; rg++){
      int co = co_t + m*16 + rg;
      float bias = cbias[b*COUT + co];
      float s1 = 0.f, s2 = 0.f;
      size_t base = (size_t)co * NPX + px_t;
#pragma unroll
      for (int n = 0; n < 4; n++){
        float v = acc[m][n][rg] + bias;
        outb[base + n*16] = v;
        s1 += v; s2 += v*v;
      }
#pragma unroll
      for (int o = 8; o; o >>= 1){ s1 += __shfl_xor(s1, o); s2 += __shfl_xor(s2, o); }
      if (l15 == 0){ atomicAdd(&ssum[co], s1); atomicAdd(&ssq[co], s2); }
    }
  }
}

// ---------------- finalize BN scale/shift ----------------
__global__ void k_stats(const float* __restrict__ ssum, const float* __restrict__ ssq,
                        const float* __restrict__ gamma, const float* __restrict__ beta,
                        float* __restrict__ sc, float* __restrict__ sh){
  int co = blockIdx.x*256 + threadIdx.x;    // 512
  const float invN = 1.0f / 65536.0f;
  float m  = ssum[co] * invN;
  float var = ssq[co] * invN - m*m;
  float scale = gamma[co] * rsqrtf(var + 1e-5f);
  sc[co] = scale;
  sh[co] = beta[co] - m*scale;
}

// ---------------- normalize + LeakyReLU (in place on d_out) ----------------
__global__ void k_norm(float* __restrict__ out, const float* __restrict__ sc,
                       const float* __restrict__ sh){
  const int NF4 = (NB*COUT*NPX)/4;          // 8388608
  int idx = blockIdx.x*256 + threadIdx.x;   // grid 8192*256
  float4* o4 = (float4*)out;
  for (int i = idx; i < NF4; i += 8192*256){
    float4 v = o4[i];
    int co = (i >> 10) & 511;
    float a = sc[co], d = sh[co];
    v.x = fmaf(v.x, a, d); v.y = fmaf(v.y, a, d);
    v.z = fmaf(v.z, a, d); v.w = fmaf(v.w, a, d);
    v.x = v.x > 0.f ? v.x : 0.1f*v.x;
    v.y = v.y > 0.f ? v.y : 0.1f*v.y;
    v.z = v.z > 0.f ? v.z : 0.1f*v.z;
    v.w = v.w > 0.f ? v.w : 0.1f*v.w;
    o4[i] = v;
  }
}

extern "C" void kernel_launch(void* const* d_in, const int* in_sizes, int n_in,
                              void* d_out, int out_size, void* d_ws, size_t ws_size,
                              hipStream_t stream) {
  const float* x     = (const float*)d_in[0];
  const float* ew    = (const float*)d_in[1];
  const float* eb    = (const float*)d_in[2];
  const float* fcw   = (const float*)d_in[3];
  const float* fcb   = (const float*)d_in[4];
  const float* gamma = (const float*)d_in[5];
  const float* beta  = (const float*)d_in[6];
  float* out = (float*)d_out;

  char* ws = (char*)d_ws;
  const size_t XT_BYTES = (size_t)NB*66*68*CIN*2;          // 36,765,696
  const size_t WC_BYTES = (size_t)NB*NSTEP*COUT*32*2;      // 37,748,736
  u16* xt = (u16*)ws;
  u16* wc = (u16*)(ws + XT_BYTES);
  float* fbase   = (float*)(ws + XT_BYTES + WC_BYTES);
  float* pooled  = fbase;                 // 4096 (zeroed)
  float* ssum    = fbase + 4096;          // 512  (zeroed)
  float* ssq     = fbase + 4608;          // 512  (zeroed)
  float* routing = fbase + 5120;          // 128
  float* cbias   = fbase + 5248;          // 8192
  float* sc      = fbase + 13440;         // 512
  float* sh      = fbase + 13952;         // 512

  hipMemsetAsync(xt, 0, XT_BYTES, stream);
  hipMemsetAsync(pooled, 0, 5120*sizeof(float), stream);   // pooled+ssum+ssq

  k_xprep<<<4096, 256, 0, stream>>>(x, xt, pooled);
  k_route<<<128,   64, 0, stream>>>(pooled, fcw, fcb, routing);
  k_cbias<<<32,   256, 0, stream>>>(routing, eb, cbias);
  k_wcomb<<<4608, 256, 0, stream>>>(routing, ew, wc);
  k_conv <<<2048, 256, 0, stream>>>(xt, wc, cbias, out, ssum, ssq);
  k_stats<<<2,    256, 0, stream>>>(ssum, ssq, gamma, beta, sc, sh);
  k_norm <<<8192, 256, 0, stream>>>(out, sc, sh);
}